// Round 3
// baseline (6785.322 us; speedup 1.0000x reference)
//
#include <hip/hip_runtime.h>
#include <math.h>

#define BATCH 64
#define SEQ   512
#define DIMK  1024
#define HID   1024
#define NWG   256         // 128 col-groups x 2 batch-halves
#define BLK   512
#define HPW   8           // hidden columns per WG
#define NCOL  32          // 4 gates * HPW
#define BPAD  1032        // LDS col stride (1024 + 8)
#define BH    (BATCH * HID)
#define ROWS  32          // batch rows per WG
#define SCRW  (NCOL + 4)

typedef _Float16 h8  __attribute__((ext_vector_type(8)));
typedef float    f4  __attribute__((ext_vector_type(4)));
typedef float    fv4 __attribute__((ext_vector_type(4)));
typedef unsigned long long u64;

#define MFMA(a, b, c) __builtin_amdgcn_mfma_f32_16x16x32_f16(a, b, c, 0, 0, 0)

// 16-B fragment load, LLC-coherent, bypasses L1/L2 — no fences needed.
__device__ __forceinline__ h8 ldh8_llc(const _Float16* p){
    union { u64 q[2]; h8 v; } r;
    const u64* q = (const u64*)p;
    r.q[0] = __hip_atomic_load((u64*)(q + 0), __ATOMIC_RELAXED, __HIP_MEMORY_SCOPE_AGENT);
    r.q[1] = __hip_atomic_load((u64*)(q + 1), __ATOMIC_RELAXED, __HIP_MEMORY_SCOPE_AGENT);
    return r.v;
}

__device__ __forceinline__ unsigned umin_(unsigned a, unsigned b){ return a < b ? a : b; }

// Fast gate math: native exp2-based exp + v_rcp. Saturates correctly at +-inf.
__device__ __forceinline__ float fsig(float z){
    return __builtin_amdgcn_rcpf(1.f + __expf(-z));
}
__device__ __forceinline__ float ftanh(float z){
    return 1.f - 2.f * __builtin_amdgcn_rcpf(1.f + __expf(2.f * z));
}

// Stage 32 columns (4 gates x 8 hidden) of four fp32 matrices into LDS as fp16 hi+lo planes.
__device__ __forceinline__ void stage32(const float* const M[4], int hb,
                                        _Float16* BlH, _Float16* BlL){
    int jj = threadIdx.x & 7;
    int kk = threadIdx.x >> 3;          // 0..63
    #pragma unroll
    for (int g = 0; g < 4; ++g){
        const float* Mg = M[g];
        #pragma unroll
        for (int it = 0; it < 16; ++it){
            int k = kk + 64 * it;
            float v = Mg[(long)k * HID + hb + jj];
            _Float16 hi = (_Float16)v;
            _Float16 lo = (_Float16)(v - (float)hi);
            BlH[(g * HPW + jj) * BPAD + k] = hi;
            BlL[(g * HPW + jj) * BPAD + k] = lo;
        }
    }
}

__global__ void __launch_bounds__(BLK, 2)
lstm_kernel(const float* x,
            const float* wf, const float* wi, const float* wo, const float* wc,
            const float* uf, const float* ui, const float* uo, const float* uc,
            const float* bfp, const float* bip, const float* bop, const float* bcp,
            float* out, unsigned* flags, _Float16* hbuf)
{
    // LDS arena: [BlH | BlL | scrA]. scrB aliases BlH (staging dead once B-regs loaded).
    __shared__ __align__(16) char arena[2 * NCOL * BPAD * 2 + 4 * ROWS * SCRW * 4];
    _Float16* BlH = (_Float16*)arena;
    _Float16* BlL = BlH + NCOL * BPAD;
    float (*scrA)[ROWS][SCRW] = (float (*)[ROWS][SCRW])(arena + 2 * NCOL * BPAD * 2);
    float (*scrB)[ROWS][SCRW] = (float (*)[ROWS][SCRW])(arena);

    const int tid  = threadIdx.x;
    const int lane = tid & 63;
    const int wave = tid >> 6;
    const int mt   = wave & 1;          // m-tile (16 rows of the 32-row slice)
    const int ks   = wave >> 1;         // k-quarter (256)
    const int cg   = blockIdx.x >> 1;   // col-group
    const int bh   = blockIdx.x & 1;    // batch half
    const int hb   = cg * HPW;

    const int arow = mt * 16 + (lane & 15);      // local row 0..31
    const int grow = bh * ROWS + arow;           // global batch row
    const int kb   = ks * 256 + ((lane >> 4) * 8);
    const int bcol = lane & 15;

    const float* Ws[4] = {wf, wi, wo, wc};
    const float* Us[4] = {uf, ui, uo, uc};

    // ---- Phase 0: gx = x0 @ W + b ----
    stage32(Ws, hb, BlH, BlL);
    __syncthreads();

    f4 acc0 = {0.f,0.f,0.f,0.f}, acc1 = {0.f,0.f,0.f,0.f};
    {
        const float* Ar = x + (long)grow * (SEQ * DIMK);
        #pragma unroll
        for (int i = 0; i < 8; ++i){
            int k = kb + i * 32;
            fv4 xa = *(const fv4*)(Ar + k);
            fv4 xb = *(const fv4*)(Ar + k + 4);
            h8 xhi, xlo;
            #pragma unroll
            for (int j = 0; j < 4; ++j){
                xhi[j]   = (_Float16)xa[j];  xlo[j]   = (_Float16)(xa[j] - (float)xhi[j]);
                xhi[4+j] = (_Float16)xb[j];  xlo[4+j] = (_Float16)(xb[j] - (float)xhi[4+j]);
            }
            h8 b0h = *(const h8*)&BlH[ bcol       * BPAD + k];
            h8 b1h = *(const h8*)&BlH[(16 + bcol) * BPAD + k];
            h8 b0l = *(const h8*)&BlL[ bcol       * BPAD + k];
            h8 b1l = *(const h8*)&BlL[(16 + bcol) * BPAD + k];
            acc0 = MFMA(xhi, b0h, acc0); acc0 = MFMA(xlo, b0h, acc0); acc0 = MFMA(xhi, b0l, acc0);
            acc1 = MFMA(xhi, b1h, acc1); acc1 = MFMA(xlo, b1h, acc1); acc1 = MFMA(xhi, b1l, acc1);
        }
    }
    {
        int r0 = mt * 16 + ((lane >> 4) << 2);
        #pragma unroll
        for (int r = 0; r < 4; ++r){
            scrA[ks][r0 + r][bcol]      = acc0[r];
            scrA[ks][r0 + r][16 + bcol] = acc1[r];
        }
    }
    __syncthreads();

    const int eb = tid >> 3;            // local batch row (waves 0-3)
    const int ej = tid & 7;             // hidden col within WG slice
    float gx0 = 0.f, gx1 = 0.f, gx2 = 0.f, gx3 = 0.f;
    if (wave < 4){
        gx0 = scrA[0][eb][ 0+ej] + scrA[1][eb][ 0+ej] + scrA[2][eb][ 0+ej] + scrA[3][eb][ 0+ej] + bfp[hb + ej];
        gx1 = scrA[0][eb][ 8+ej] + scrA[1][eb][ 8+ej] + scrA[2][eb][ 8+ej] + scrA[3][eb][ 8+ej] + bip[hb + ej];
        gx2 = scrA[0][eb][16+ej] + scrA[1][eb][16+ej] + scrA[2][eb][16+ej] + scrA[3][eb][16+ej] + bop[hb + ej];
        gx3 = scrA[0][eb][24+ej] + scrA[1][eb][24+ej] + scrA[2][eb][24+ej] + scrA[3][eb][24+ej] + bcp[hb + ej];
    }
    stage32(Us, hb, BlH, BlL);          // stage U once
    __syncthreads();

    // ---- U fragments into registers: invariant across all 512 steps ----
    h8 Bh0[8], Bh1[8], Bl0[8], Bl1[8];
    #pragma unroll
    for (int i = 0; i < 8; ++i){
        int k = kb + i * 32;
        Bh0[i] = *(const h8*)&BlH[ bcol       * BPAD + k];
        Bh1[i] = *(const h8*)&BlH[(16 + bcol) * BPAD + k];
        Bl0[i] = *(const h8*)&BlL[ bcol       * BPAD + k];
        Bl1[i] = *(const h8*)&BlL[(16 + bcol) * BPAD + k];
    }

    // ---- Dataflow flags: flags[bh][cg][w], u32, 16B per cg-quad ----
    // Producer: wave w (<4) owns h rows [8w,8w+8) of its half, cols [hb,hb+8).
    unsigned* myflag = flags + ((((bh << 7) + cg) << 2) + wave);
    // Consumer: wave (any) needs all 4 producer waves of cgs [ks*32, ks*32+32) of its half.
    const u64* fq = (const u64*)(flags + (((bh << 7) + (ks << 5) + (lane & 31)) << 2));

    // ---- Recurrence: 512 steps, per-wave dataflow sync, ONE syncthreads/step ----
    float cstate = 0.f;
    const int  orow  = bh * ROWS + eb;
    const long obase = (long)orow * (SEQ * HID) + hb + ej;

    for (int t = 0; t < SEQ; ++t){
        // Wait for h(t): producers published flag==t after storing h(t). t=0 trivially ready.
        if (t){
            const unsigned tgt = (unsigned)t;
            for (;;){
                u64 q0 = __hip_atomic_load(fq + 0, __ATOMIC_RELAXED, __HIP_MEMORY_SCOPE_AGENT);
                u64 q1 = __hip_atomic_load(fq + 1, __ATOMIC_RELAXED, __HIP_MEMORY_SCOPE_AGENT);
                unsigned mn = umin_(umin_((unsigned)q0, (unsigned)(q0 >> 32)),
                                    umin_((unsigned)q1, (unsigned)(q1 >> 32)));
                if (__all((int)(mn >= tgt))) break;
                __builtin_amdgcn_s_sleep(1);
            }
        }
        asm volatile("" ::: "memory");   // keep A-loads below the poll

        const _Float16* hcH = hbuf + (t & 1) * (2 * BH);
        const _Float16* hcL = hcH + BH;

        h8 aH[8], aL[8];
        const _Float16* ApH = hcH + grow * HID + kb;
        const _Float16* ApL = hcL + grow * HID + kb;
        #pragma unroll
        for (int i = 0; i < 8; ++i) aH[i] = ldh8_llc(ApH + i * 32);
        #pragma unroll
        for (int i = 0; i < 8; ++i) aL[i] = ldh8_llc(ApL + i * 32);

        f4 z0 = {0.f,0.f,0.f,0.f}, z1 = {0.f,0.f,0.f,0.f};
        #pragma unroll
        for (int i = 0; i < 8; ++i){
            z0 = MFMA(aH[i], Bh0[i], z0); z0 = MFMA(aL[i], Bh0[i], z0); z0 = MFMA(aH[i], Bl0[i], z0);
            z1 = MFMA(aH[i], Bh1[i], z1); z1 = MFMA(aL[i], Bh1[i], z1); z1 = MFMA(aH[i], Bl1[i], z1);
        }

        float (*scr)[ROWS][SCRW] = (t & 1) ? scrB : scrA;   // step-parity double buffer
        {
            int r0 = mt * 16 + ((lane >> 4) << 2);
            #pragma unroll
            for (int r = 0; r < 4; ++r){
                scr[ks][r0 + r][bcol]      = z0[r];
                scr[ks][r0 + r][16 + bcol] = z1[r];
            }
        }
        __syncthreads();                 // the ONLY per-step barrier: scr exchange

        if (wave < 4){
            float zf = gx0 + scr[0][eb][ 0+ej] + scr[1][eb][ 0+ej] + scr[2][eb][ 0+ej] + scr[3][eb][ 0+ej];
            float zi = gx1 + scr[0][eb][ 8+ej] + scr[1][eb][ 8+ej] + scr[2][eb][ 8+ej] + scr[3][eb][ 8+ej];
            float zo = gx2 + scr[0][eb][16+ej] + scr[1][eb][16+ej] + scr[2][eb][16+ej] + scr[3][eb][16+ej];
            float zc = gx3 + scr[0][eb][24+ej] + scr[1][eb][24+ej] + scr[2][eb][24+ej] + scr[3][eb][24+ej];
            float f  = fsig(zf);
            float ii = fsig(zi);
            float o  = fsig(zo);
            float ch = ftanh(zc);
            cstate   = f * cstate + ii * ch;
            float hv = o * ftanh(cstate);

            if (t < SEQ - 1){
                _Float16* hnH = hbuf + ((t + 1) & 1) * (2 * BH);
                _Float16* hnL = hnH + BH;
                _Float16 hhi = (_Float16)hv;
                _Float16 hlo = (_Float16)(hv - (float)hhi);
                unsigned uhi = (unsigned short)__builtin_bit_cast(unsigned short, hhi);
                unsigned ulo = (unsigned short)__builtin_bit_cast(unsigned short, hlo);
                unsigned phi = (unsigned)__shfl_xor((int)uhi, 1);
                unsigned plo = (unsigned)__shfl_xor((int)ulo, 1);
                if (!(ej & 1)){          // even col: store packed dword (this + partner)
                    int widx = (orow * HID + hb + ej) >> 1;
                    __hip_atomic_store((unsigned*)hnH + widx, uhi | (phi << 16),
                                       __ATOMIC_RELAXED, __HIP_MEMORY_SCOPE_AGENT);
                    __hip_atomic_store((unsigned*)hnL + widx, ulo | (plo << 16),
                                       __ATOMIC_RELAXED, __HIP_MEMORY_SCOPE_AGENT);
                }
                asm volatile("s_waitcnt vmcnt(0)" ::: "memory");   // own h-stores acked at LLC
                if (lane == 0)
                    __hip_atomic_store(myflag, (unsigned)(t + 1),
                                       __ATOMIC_RELAXED, __HIP_MEMORY_SCOPE_AGENT);
            }
            out[obase + (long)t * HID] = hv;   // after flag: not on the critical chain
        }
    }
}

extern "C" void kernel_launch(void* const* d_in, const int* in_sizes, int n_in,
                              void* d_out, int out_size, void* d_ws, size_t ws_size,
                              hipStream_t stream)
{
    const float* x  = (const float*)d_in[0];
    const float* wf = (const float*)d_in[1];
    const float* wi = (const float*)d_in[2];
    const float* wo = (const float*)d_in[3];
    const float* wc = (const float*)d_in[4];
    const float* uf = (const float*)d_in[5];
    const float* ui = (const float*)d_in[6];
    const float* uo = (const float*)d_in[7];
    const float* uc = (const float*)d_in[8];
    const float* bf = (const float*)d_in[9];
    const float* bi = (const float*)d_in[10];
    const float* bo = (const float*)d_in[11];
    const float* bc = (const float*)d_in[12];
    float* out = (float*)d_out;

    unsigned*  flags = (unsigned*)d_ws;                       // [2][128][4] u32 epoch flags
    _Float16*  hbuf  = (_Float16*)((char*)d_ws + 32768);      // h ping-pong (hi+lo planes)

    // zero flags + both h ping-pong buffers; h0 = 0, flag epoch 0 == "h(0) ready"
    hipMemsetAsync(d_ws, 0, 32768 + (size_t)2 * 2 * BH * sizeof(_Float16), stream);

    void* args[] = { &x, &wf, &wi, &wo, &wc, &uf, &ui, &uo, &uc,
                     &bf, &bi, &bo, &bc, &out, &flags, &hbuf };
    hipLaunchCooperativeKernel((void*)lstm_kernel, dim3(NWG), dim3(BLK), args, 0, stream);
}

// Round 4
// 6436.804 us; speedup vs baseline: 1.0541x; 1.0541x over previous
//
#include <hip/hip_runtime.h>
#include <math.h>

#define BATCH 64
#define SEQ   512
#define DIMK  1024
#define HID   1024
#define NWG   256         // 128 col-groups x 2 batch-halves
#define BLK   512
#define HPW   8           // hidden columns per WG
#define NCOL  32          // 4 gates * HPW
#define BPAD  1032        // LDS col stride (1024 + 8)
#define BH    (BATCH * HID)
#define ROWS  32          // batch rows per WG
#define SCRW  (NCOL + 4)

typedef _Float16 h8  __attribute__((ext_vector_type(8)));
typedef float    f4  __attribute__((ext_vector_type(4)));
typedef float    fv4 __attribute__((ext_vector_type(4)));
typedef unsigned long long u64;

#define MFMA(a, b, c) __builtin_amdgcn_mfma_f32_16x16x32_f16(a, b, c, 0, 0, 0)

// 16-B fragment load, LLC-coherent, bypasses L1/L2 — no fences needed.
__device__ __forceinline__ h8 ldh8_llc(const _Float16* p){
    union { u64 q[2]; h8 v; } r;
    const u64* q = (const u64*)p;
    r.q[0] = __hip_atomic_load((u64*)(q + 0), __ATOMIC_RELAXED, __HIP_MEMORY_SCOPE_AGENT);
    r.q[1] = __hip_atomic_load((u64*)(q + 1), __ATOMIC_RELAXED, __HIP_MEMORY_SCOPE_AGENT);
    return r.v;
}

// Fast gate math: native exp2-based exp + v_rcp. Saturates correctly at +-inf.
__device__ __forceinline__ float fsig(float z){
    return __builtin_amdgcn_rcpf(1.f + __expf(-z));
}
__device__ __forceinline__ float ftanh(float z){
    return 1.f - 2.f * __builtin_amdgcn_rcpf(1.f + __expf(2.f * z));
}

// Stage 32 columns (4 gates x 8 hidden) of four fp32 matrices into LDS as fp16 hi+lo planes.
__device__ __forceinline__ void stage32(const float* const M[4], int hb,
                                        _Float16* BlH, _Float16* BlL){
    int jj = threadIdx.x & 7;
    int kk = threadIdx.x >> 3;          // 0..63
    #pragma unroll
    for (int g = 0; g < 4; ++g){
        const float* Mg = M[g];
        #pragma unroll
        for (int it = 0; it < 16; ++it){
            int k = kk + 64 * it;
            float v = Mg[(long)k * HID + hb + jj];
            _Float16 hi = (_Float16)v;
            _Float16 lo = (_Float16)(v - (float)hi);
            BlH[(g * HPW + jj) * BPAD + k] = hi;
            BlL[(g * HPW + jj) * BPAD + k] = lo;
        }
    }
}

__global__ void __launch_bounds__(BLK, 2)
lstm_kernel(const float* x,
            const float* wf, const float* wi, const float* wo, const float* wc,
            const float* uf, const float* ui, const float* uo, const float* uc,
            const float* bfp, const float* bip, const float* bop, const float* bcp,
            float* out, unsigned* flags, _Float16* hbuf)
{
    // LDS arena: [BlH | BlL | scrA]. scrB aliases BlH (staging dead once B-regs loaded).
    __shared__ __align__(16) char arena[2 * NCOL * BPAD * 2 + 4 * ROWS * SCRW * 4];
    __shared__ unsigned lds_cnt;        // monotone producer-arrival counter
    _Float16* BlH = (_Float16*)arena;
    _Float16* BlL = BlH + NCOL * BPAD;
    float (*scrA)[ROWS][SCRW] = (float (*)[ROWS][SCRW])(arena + 2 * NCOL * BPAD * 2);
    float (*scrB)[ROWS][SCRW] = (float (*)[ROWS][SCRW])(arena);

    const int tid  = threadIdx.x;
    const int lane = tid & 63;
    const int wave = tid >> 6;
    const int mt   = wave & 1;          // m-tile (16 rows of the 32-row slice)
    const int ks   = wave >> 1;         // k-quarter (256)
    const int cg   = blockIdx.x >> 1;   // col-group
    const int bh   = blockIdx.x & 1;    // batch half
    const int hb   = cg * HPW;

    const int arow = mt * 16 + (lane & 15);      // local row 0..31
    const int grow = bh * ROWS + arow;           // global batch row
    const int kb   = ks * 256 + ((lane >> 4) * 8);
    const int bcol = lane & 15;

    const float* Ws[4] = {wf, wi, wo, wc};
    const float* Us[4] = {uf, ui, uo, uc};

    // ---- Phase 0: gx = x0 @ W + b ----
    stage32(Ws, hb, BlH, BlL);
    __syncthreads();

    f4 acc0 = {0.f,0.f,0.f,0.f}, acc1 = {0.f,0.f,0.f,0.f};
    {
        const float* Ar = x + (long)grow * (SEQ * DIMK);
        #pragma unroll
        for (int i = 0; i < 8; ++i){
            int k = kb + i * 32;
            fv4 xa = *(const fv4*)(Ar + k);
            fv4 xb = *(const fv4*)(Ar + k + 4);
            h8 xhi, xlo;
            #pragma unroll
            for (int j = 0; j < 4; ++j){
                xhi[j]   = (_Float16)xa[j];  xlo[j]   = (_Float16)(xa[j] - (float)xhi[j]);
                xhi[4+j] = (_Float16)xb[j];  xlo[4+j] = (_Float16)(xb[j] - (float)xhi[4+j]);
            }
            h8 b0h = *(const h8*)&BlH[ bcol       * BPAD + k];
            h8 b1h = *(const h8*)&BlH[(16 + bcol) * BPAD + k];
            h8 b0l = *(const h8*)&BlL[ bcol       * BPAD + k];
            h8 b1l = *(const h8*)&BlL[(16 + bcol) * BPAD + k];
            acc0 = MFMA(xhi, b0h, acc0); acc0 = MFMA(xlo, b0h, acc0); acc0 = MFMA(xhi, b0l, acc0);
            acc1 = MFMA(xhi, b1h, acc1); acc1 = MFMA(xlo, b1h, acc1); acc1 = MFMA(xhi, b1l, acc1);
        }
    }
    {
        int r0 = mt * 16 + ((lane >> 4) << 2);
        #pragma unroll
        for (int r = 0; r < 4; ++r){
            scrA[ks][r0 + r][bcol]      = acc0[r];
            scrA[ks][r0 + r][16 + bcol] = acc1[r];
        }
    }
    __syncthreads();

    const int eb = tid >> 3;            // local batch row (waves 0-3)
    const int ej = tid & 7;             // hidden col within WG slice
    float gx0 = 0.f, gx1 = 0.f, gx2 = 0.f, gx3 = 0.f;
    if (wave < 4){
        gx0 = scrA[0][eb][ 0+ej] + scrA[1][eb][ 0+ej] + scrA[2][eb][ 0+ej] + scrA[3][eb][ 0+ej] + bfp[hb + ej];
        gx1 = scrA[0][eb][ 8+ej] + scrA[1][eb][ 8+ej] + scrA[2][eb][ 8+ej] + scrA[3][eb][ 8+ej] + bip[hb + ej];
        gx2 = scrA[0][eb][16+ej] + scrA[1][eb][16+ej] + scrA[2][eb][16+ej] + scrA[3][eb][16+ej] + bop[hb + ej];
        gx3 = scrA[0][eb][24+ej] + scrA[1][eb][24+ej] + scrA[2][eb][24+ej] + scrA[3][eb][24+ej] + bcp[hb + ej];
    }
    if (tid == 0) lds_cnt = 0;
    stage32(Us, hb, BlH, BlL);          // stage U once
    __syncthreads();

    // ---- U fragments into registers: invariant across all 512 steps ----
    h8 Bh0[8], Bh1[8], Bl0[8], Bl1[8];
    #pragma unroll
    for (int i = 0; i < 8; ++i){
        int k = kb + i * 32;
        Bh0[i] = *(const h8*)&BlH[ bcol       * BPAD + k];
        Bh1[i] = *(const h8*)&BlH[(16 + bcol) * BPAD + k];
        Bl0[i] = *(const h8*)&BlL[ bcol       * BPAD + k];
        Bl1[i] = *(const h8*)&BlL[(16 + bcol) * BPAD + k];
    }

    // ---- Dataflow flags: flags[bh][cg], ONE u32 per col-group (1 KB total) ----
    // Published by the last of the 4 producer waves (LDS-counter combine).
    // Consumer wave (quarter ks) polls only its 32 source col-groups: 4 B/lane.
    const unsigned* pollp = flags + (bh << 7) + (ks << 5) + (lane & 31);
    unsigned* pubp = flags + (bh << 7) + cg;

    // ---- Recurrence: 512 steps, per-quarter dataflow sync, ONE syncthreads/step ----
    float cstate = 0.f;
    const int  orow  = bh * ROWS + eb;
    const long obase = (long)orow * (SEQ * HID) + hb + ej;

    for (int t = 0; t < SEQ; ++t){
        // Wait for h(t): flags[bh][cg]==t means cg's h(t) cols are LLC-visible.
        if (t){
            const unsigned tgt = (unsigned)t;
            for (;;){
                unsigned f = __hip_atomic_load(pollp, __ATOMIC_RELAXED, __HIP_MEMORY_SCOPE_AGENT);
                if (__all((int)(f >= tgt))) break;
                __builtin_amdgcn_s_sleep(1);
            }
        }
        asm volatile("" ::: "memory");   // keep A-loads below the poll

        const _Float16* hcH = hbuf + (t & 1) * (2 * BH);
        const _Float16* hcL = hcH + BH;

        h8 aH[8], aL[8];
        const _Float16* ApH = hcH + grow * HID + kb;
        const _Float16* ApL = hcL + grow * HID + kb;
        #pragma unroll
        for (int i = 0; i < 8; ++i) aH[i] = ldh8_llc(ApH + i * 32);
        #pragma unroll
        for (int i = 0; i < 8; ++i) aL[i] = ldh8_llc(ApL + i * 32);

        f4 z0 = {0.f,0.f,0.f,0.f}, z1 = {0.f,0.f,0.f,0.f};
        #pragma unroll
        for (int i = 0; i < 8; ++i){
            z0 = MFMA(aH[i], Bh0[i], z0); z0 = MFMA(aL[i], Bh0[i], z0); z0 = MFMA(aH[i], Bl0[i], z0);
            z1 = MFMA(aH[i], Bh1[i], z1); z1 = MFMA(aL[i], Bh1[i], z1); z1 = MFMA(aH[i], Bl1[i], z1);
        }

        float (*scr)[ROWS][SCRW] = (t & 1) ? scrB : scrA;   // step-parity double buffer
        {
            int r0 = mt * 16 + ((lane >> 4) << 2);
            #pragma unroll
            for (int r = 0; r < 4; ++r){
                scr[ks][r0 + r][bcol]      = z0[r];
                scr[ks][r0 + r][16 + bcol] = z1[r];
            }
        }
        __syncthreads();                 // the ONLY per-step barrier: scr exchange

        if (wave < 4){
            float zf = gx0 + scr[0][eb][ 0+ej] + scr[1][eb][ 0+ej] + scr[2][eb][ 0+ej] + scr[3][eb][ 0+ej];
            float zi = gx1 + scr[0][eb][ 8+ej] + scr[1][eb][ 8+ej] + scr[2][eb][ 8+ej] + scr[3][eb][ 8+ej];
            float zo = gx2 + scr[0][eb][16+ej] + scr[1][eb][16+ej] + scr[2][eb][16+ej] + scr[3][eb][16+ej];
            float zc = gx3 + scr[0][eb][24+ej] + scr[1][eb][24+ej] + scr[2][eb][24+ej] + scr[3][eb][24+ej];
            float f  = fsig(zf);
            float ii = fsig(zi);
            float o  = fsig(zo);
            float ch = ftanh(zc);
            cstate   = f * cstate + ii * ch;
            float hv = o * ftanh(cstate);

            if (t < SEQ - 1){
                _Float16* hnH = hbuf + ((t + 1) & 1) * (2 * BH);
                _Float16* hnL = hnH + BH;
                _Float16 hhi = (_Float16)hv;
                _Float16 hlo = (_Float16)(hv - (float)hhi);
                unsigned uhi = (unsigned short)__builtin_bit_cast(unsigned short, hhi);
                unsigned ulo = (unsigned short)__builtin_bit_cast(unsigned short, hlo);
                unsigned phi = (unsigned)__shfl_xor((int)uhi, 1);
                unsigned plo = (unsigned)__shfl_xor((int)ulo, 1);
                if (!(ej & 1)){          // even col: store packed dword (this + partner)
                    int widx = (orow * HID + hb + ej) >> 1;
                    __hip_atomic_store((unsigned*)hnH + widx, uhi | (phi << 16),
                                       __ATOMIC_RELAXED, __HIP_MEMORY_SCOPE_AGENT);
                    __hip_atomic_store((unsigned*)hnL + widx, ulo | (plo << 16),
                                       __ATOMIC_RELAXED, __HIP_MEMORY_SCOPE_AGENT);
                }
                asm volatile("s_waitcnt vmcnt(0)" ::: "memory");   // own h-stores acked at LLC
                if (lane == 0){
                    unsigned old = __hip_atomic_fetch_add(&lds_cnt, 1u, __ATOMIC_RELAXED,
                                                          __HIP_MEMORY_SCOPE_WORKGROUP);
                    if (old == 4u * (unsigned)t + 3u)   // last producer wave of this step
                        __hip_atomic_store(pubp, (unsigned)(t + 1),
                                           __ATOMIC_RELAXED, __HIP_MEMORY_SCOPE_AGENT);
                }
            }
            out[obase + (long)t * HID] = hv;   // after publish: off the critical chain
        }
    }
}

extern "C" void kernel_launch(void* const* d_in, const int* in_sizes, int n_in,
                              void* d_out, int out_size, void* d_ws, size_t ws_size,
                              hipStream_t stream)
{
    const float* x  = (const float*)d_in[0];
    const float* wf = (const float*)d_in[1];
    const float* wi = (const float*)d_in[2];
    const float* wo = (const float*)d_in[3];
    const float* wc = (const float*)d_in[4];
    const float* uf = (const float*)d_in[5];
    const float* ui = (const float*)d_in[6];
    const float* uo = (const float*)d_in[7];
    const float* uc = (const float*)d_in[8];
    const float* bf = (const float*)d_in[9];
    const float* bi = (const float*)d_in[10];
    const float* bo = (const float*)d_in[11];
    const float* bc = (const float*)d_in[12];
    float* out = (float*)d_out;

    unsigned*  flags = (unsigned*)d_ws;                       // [2][128] u32 epoch flags
    _Float16*  hbuf  = (_Float16*)((char*)d_ws + 32768);      // h ping-pong (hi+lo planes)

    // zero flags + both h ping-pong buffers; h0 = 0, flag epoch 0 == "h(0) ready"
    hipMemsetAsync(d_ws, 0, 32768 + (size_t)2 * 2 * BH * sizeof(_Float16), stream);

    void* args[] = { &x, &wf, &wi, &wo, &wc, &uf, &ui, &uo, &uc,
                     &bf, &bi, &bo, &bc, &out, &flags, &hbuf };
    hipLaunchCooperativeKernel((void*)lstm_kernel, dim3(NWG), dim3(BLK), args, 0, stream);
}